// Round 8
// baseline (229.180 us; speedup 1.0000x reference)
//
#include <hip/hip_runtime.h>
#include <hip/hip_bf16.h>
#include <math.h>

#define Bn 8
#define Cn 96
#define Hn 128
#define Wn 128
#define PLANE (Hn*Wn)          // 16384
#define NIMG (Bn*Cn*PLANE)     // 12582912
#define EPSV 1e-5f
#define TAPN 48
#define TAPF 8

typedef __attribute__((ext_vector_type(8))) short short8;
typedef __attribute__((ext_vector_type(4))) float floatx4;

union FragU { short8 v; uint2 u2[2]; };

// ---------------------------------------------------------------------------
// K0: merged sparse tap lists (LDS dense accumulator) + w_fuse -> bf16.
// One block; w conversion uses all 256 threads (was done redundantly by
// every k2 block).
// ---------------------------------------------------------------------------
__global__ __launch_bounds__(256) void k0_taps(
    const float* __restrict__ rm_p, const float* __restrict__ whm, const float* __restrict__ wwm,
    const float* __restrict__ rl_p, const float* __restrict__ whl, const float* __restrict__ wwl,
    const float* __restrict__ w_fuse,
    int* __restrict__ cnt, int* __restrict__ offs, float* __restrict__ wts,
    short* __restrict__ w_bf)
{
    __shared__ float dense[2 * Cn][TAPN + 1];   // 192 x 49 floats = 37632 B

    int t = threadIdx.x;              // 0..255
    // w_fuse -> bf16 (all threads)
    for (int e = t; e < Cn * Cn; e += 256) {
        __hip_bfloat16 hv = __float2bfloat16(w_fuse[e]);
        w_bf[e] = *(short*)&hv;
    }
    // zero LDS (all 256 threads)
    for (int e = t; e < 2 * Cn * (TAPN + 1); e += 256)
        ((float*)dense)[e] = 0.f;
    __syncthreads();

    if (t >= Cn * 2) return;
    int c = t >> 1, dir = t & 1;
    const float* tap_m = dir ? (wwm + c * 5) : (whm + c * 5);
    const float* tap_l = dir ? (wwl + c * 5) : (whl + c * 5);
    float rm = fmaxf(rm_p[0], 1.f), rl = fmaxf(rl_p[0], 1.f);
    for (int pass = 0; pass < 2; ++pass) {
        float r = pass ? rl : rm;
        const float* tp = pass ? tap_l : tap_m;
        for (int i = 0; i < 5; ++i) {
            float s = (float)(i - 2) * r;
            float f = floorf(s);
            float fr = s - f;
            int fi = (int)f + 23;
            if (fi >= 0 && fi < TAPN)         dense[t][fi]     += tp[i] * (1.f - fr);
            if (fi + 1 >= 0 && fi + 1 < TAPN) dense[t][fi + 1] += tp[i] * fr;
        }
    }
    // compact row t -> global, writing all 48 slots (entries then zeros)
    int n = 0;
    int*   orow = offs + t * TAPN;
    float* wrow = wts  + t * TAPN;
    for (int k = 0; k < TAPN; ++k) {
        float wv = dense[t][k];
        if (wv != 0.f) { orow[n] = k - 23; wrow[n] = wv; ++n; }
    }
    cnt[t] = n;
    for (int k = n; k < TAPN; ++k) { orow[k] = 0; wrow[k] = 0.f; }
}

// ---------------------------------------------------------------------------
// K1: t = 2x + FIR(H) + FIR(W)  (bf16, layout [b][h][c][w])
//     anchor = BN_d(x + dwconv3_h + dwconv3_w)  (fp32, layout [b][c][h][w])
// TWO blocks per (b,c) plane (64 rows each + 16-row halo staged in LDS,
// [96][160] = 61.4 KB -> 2 resident/CU, 6 blocks/CU of work: tail bubble
// of the whole-plane version removed).  Fast path requires |soH|<=16 (halo
// bound; true for r<=8); otherwise the slow global-gather path runs.
// ---------------------------------------------------------------------------
__global__ __launch_bounds__(512) void k1_axial(
    const float* __restrict__ x,
    const int* __restrict__ cnt, const int* __restrict__ offs, const float* __restrict__ wts,
    const float* __restrict__ dwh, const float* __restrict__ dww,
    const float* __restrict__ dg, const float* __restrict__ db_,
    const float* __restrict__ dm, const float* __restrict__ dv,
    short* __restrict__ t_bf, float* __restrict__ anchor,
    float* __restrict__ xw_zero)
{
    __shared__ float pl[96][160];       // rows r0-16 .. r0+79, 16-col pads

    int blk  = blockIdx.x;              // 1536
    int bc   = blk >> 1;
    int half = blk & 1;
    int r0   = half << 6;               // 0 or 64
    int b    = bc / Cn;
    int c    = bc % Cn;
    int tid  = threadIdx.x;

    if (half == 0 && tid < Wn) xw_zero[bc * Wn + tid] = 0.f;

    const float* plane = x + ((long)bc << 14);

    // ----- stage rows r0-16 .. r0+79 (clamped to plane), coalesced float4 ---
    const float4* p4 = (const float4*)plane;
#pragma unroll
    for (int it = 0; it < 6; ++it) {
        int idx = tid + it * 512;        // 0..3071
        int lr = idx >> 5, c4 = idx & 31;
        int y = r0 - 16 + lr;
        if (y >= 0 && y < Hn)
            *(float4*)&pl[lr][16 + c4 * 4] = p4[y * 32 + c4];
    }
    // ----- zero the col pads for all 96 rows -----
#pragma unroll
    for (int it = 0; it < 2; ++it) {
        int idx = tid + it * 512;        // 0..1023, need 768
        if (idx < 768) {
            int lr = idx >> 3, pq = idx & 7;
            int col = (pq < 4) ? pq * 4 : 144 + (pq - 4) * 4;
            *(float4*)&pl[lr][col] = (float4){0.f, 0.f, 0.f, 0.f};
        }
    }

    // ----- taps: uniform loads (scalar) -----
    int cH = cnt[c * 2], cW = cnt[c * 2 + 1];
    int soH[TAPF], soW[TAPF];
    float swH[TAPF], swW[TAPF];
#pragma unroll
    for (int j = 0; j < TAPF; ++j) {
        soH[j] = offs[(c * 2) * TAPN + j];
        swH[j] = wts[(c * 2) * TAPN + j];
        soW[j] = offs[(c * 2 + 1) * TAPN + j];
        swW[j] = wts[(c * 2 + 1) * TAPN + j];
    }
    bool fast = (cH <= TAPF) && (cW <= TAPF);
#pragma unroll
    for (int j = 0; j < TAPF; ++j) {
        fast = fast && (soW[j] >= -16) && (soW[j] <= 16);
        fast = fast && (soH[j] >= -16) && (soH[j] <= 16);   // halo bound
    }

    // ----- BN_d params -----
    float e0 = dwh[c * 3], e1 = dwh[c * 3 + 1], e2 = dwh[c * 3 + 2];
    float f0 = dww[c * 3], f1 = dww[c * 3 + 1], f2 = dww[c * 3 + 2];
    float dsc = dg[c] * rsqrtf(dv[c] + EPSV);
    float dof = db_[c] - dm[c] * dsc;

    __syncthreads();

    int m      = tid & 31;
    int rowgrp = tid >> 5;               // 0..15
    short* tbase = t_bf + ((long)(b * Hn) * Cn + c) * Wn;
    float* abase = anchor + ((long)bc << 14);

    for (int k = 0; k < 4; ++k) {
        int hl = k * 16 + rowgrp;        // local row 0..63
        int h  = r0 + hl;                // global row
        int lc = hl + 16;                // LDS row of h
        float vc0 = pl[lc][16 + m];
        float vc1 = pl[lc][16 + m + 32];
        float vc2 = pl[lc][16 + m + 64];
        float vc3 = pl[lc][16 + m + 96];
        float a0 = 2.f * vc0, a1 = 2.f * vc1, a2 = 2.f * vc2, a3 = 2.f * vc3;

        if (fast) {
#pragma unroll
            for (int j = 0; j < TAPF; ++j) {   // H taps (LDS, clamped+masked)
                int y = h + soH[j];
                float wt = (y >= 0 && y < Hn) ? swH[j] : 0.f;
                y = min(max(y, 0), Hn - 1);
                int ly = y - r0 + 16;          // in [0,95]
                a0 += wt * pl[ly][16 + m];
                a1 += wt * pl[ly][16 + m + 32];
                a2 += wt * pl[ly][16 + m + 64];
                a3 += wt * pl[ly][16 + m + 96];
            }
#pragma unroll
            for (int j = 0; j < TAPF; ++j) {   // W taps (LDS, padded)
                int o = soW[j];
                float wt = swW[j];
                a0 += wt * pl[lc][16 + m + o];
                a1 += wt * pl[lc][16 + m + 32 + o];
                a2 += wt * pl[lc][16 + m + 64 + o];
                a3 += wt * pl[lc][16 + m + 96 + o];
            }
        } else {
            // slow fallback: correct for any runtime r (global gathers)
            const int*   goH = offs + (c * 2 + 0) * TAPN;
            const float* gwH = wts  + (c * 2 + 0) * TAPN;
            const int*   goW = offs + (c * 2 + 1) * TAPN;
            const float* gwW = wts  + (c * 2 + 1) * TAPN;
            for (int j = 0; j < cH; ++j) {
                int y = h + goH[j];
                if (y >= 0 && y < Hn) {
                    float wt = gwH[j];
                    const float* rp = plane + (y << 7);
                    a0 += wt * rp[m];
                    a1 += wt * rp[m + 32];
                    a2 += wt * rp[m + 64];
                    a3 += wt * rp[m + 96];
                }
            }
            for (int j = 0; j < cW; ++j) {
                int o = goW[j];
                float wt = gwW[j];
                const float* rp = plane + (h << 7);
#pragma unroll
                for (int q = 0; q < 4; ++q) {
                    int xw = m + 32 * q + o;
                    float v = (xw >= 0 && xw < Wn) ? rp[xw] : 0.f;
                    float* ap = (q == 0) ? &a0 : (q == 1) ? &a1 : (q == 2) ? &a2 : &a3;
                    *ap += wt * v;
                }
            }
        }

        // ----- t (bf16) store, layout [b][h][c][w] -----
        short* tp = tbase + (long)h * (Cn * Wn);
        {
            __hip_bfloat16 h0 = __float2bfloat16(a0), h1 = __float2bfloat16(a1);
            __hip_bfloat16 h2 = __float2bfloat16(a2), h3 = __float2bfloat16(a3);
            tp[m]      = *(short*)&h0;
            tp[m + 32] = *(short*)&h1;
            tp[m + 64] = *(short*)&h2;
            tp[m + 96] = *(short*)&h3;
        }

        // ----- anchor = BN_d(x + edges) -----
        int yu = (h > 0) ? h - 1 : 0;
        int yd = (h < Hn - 1) ? h + 1 : Hn - 1;
        int lyu = yu - r0 + 16;
        int lyd = yd - r0 + 16;
        float wu = (h > 0) ? e0 : 0.f;
        float wd = (h < Hn - 1) ? e2 : 0.f;
        float* ap = abase + (h << 7);
#pragma unroll
        for (int q = 0; q < 4; ++q) {
            int col = 16 + m + 32 * q;
            float vcq = (q == 0) ? vc0 : (q == 1) ? vc1 : (q == 2) ? vc2 : vc3;
            float vu = pl[lyu][col];
            float vd = pl[lyd][col];
            float vl = pl[lc][col - 1];
            float vr = pl[lc][col + 1];
            float edges = wu * vu + e1 * vcq + wd * vd + f0 * vl + f1 * vcq + f2 * vr;
            ap[m + 32 * q] = (vcq + edges) * dsc + dof;
        }
    }
}

// ---------------------------------------------------------------------------
// K2: out = prelu( BN_f(w @ t) + anchor )  via bf16 MFMA 16x16x32.
// Block = (b, h, half): 96 outputs x 64 pixels. 4 waves x 6 m-tiles.
// Anchor values PREFETCHED into registers before the barrier/MFMA (T14):
// their ~400cy scattered-L3 latency hides under staging+MFMA instead of
// serializing the epilogue.  w comes pre-converted (bf16) from k0.
// ---------------------------------------------------------------------------
__global__ __launch_bounds__(256) void k2_pw(
    const short* __restrict__ t_bf, const float* __restrict__ anchor,
    const short* __restrict__ w_bf,
    const float* __restrict__ bg, const float* __restrict__ bb,
    const float* __restrict__ bm, const float* __restrict__ bv,
    const float* __restrict__ act_a,
    float* __restrict__ out)
{
    __shared__ short wl[Cn * 100];       // [o][c], stride 100 shorts (200 B)
    __shared__ short tl[64 * 100];       // [p_local][c], stride 100 shorts
    __shared__ float sfsc[Cn], sfof[Cn], saa[Cn];

    int tid  = threadIdx.x;
    int blk  = blockIdx.x;               // 2048
    int b    = blk >> 8;
    int r    = blk & 255;
    int h    = r >> 1;
    int hb   = r & 1;                    // pixel half
    int lane = tid & 63;
    int wv   = tid >> 6;
    int n16  = lane & 15;
    int quad = lane >> 4;

    // stage w (bf16) -> LDS, pure u32 copy
    {
        const uint* wsrc = (const uint*)w_bf;
        uint* wdst = (uint*)wl;
        for (int e = tid; e < Cn * 48; e += 256) {
            int o = e / 48, cq = e - o * 48;
            wdst[o * 50 + cq] = wsrc[e];
        }
    }
    // BN-fold + prelu params
    if (tid < Cn) {
        float s = bg[tid] * rsqrtf(bv[tid] + EPSV);
        sfsc[tid] = s;
        sfof[tid] = bb[tid] - bm[tid] * s;
        saa[tid]  = act_a[tid];
    }
    // stage t half-slab [96 c][64 w] -> LDS transposed [p][c] (4-ch packed)
    {
        const uint* trow = (const uint*)t_bf + (size_t)(b * Hn + h) * Cn * 64 + hb * 32;
#pragma unroll
        for (int rep = 0; rep < 3; ++rep) {
            int task = tid + rep * 256;  // 0..767 = 24 cgroups x 32 uint-cols
            int cg = task >> 5, j = task & 31;
            int c0 = cg * 4;
            uint v0 = trow[(c0 + 0) * 64 + j];
            uint v1 = trow[(c0 + 1) * 64 + j];
            uint v2 = trow[(c0 + 2) * 64 + j];
            uint v3 = trow[(c0 + 3) * 64 + j];
            uint2 lo, hi;
            lo.x = (v0 & 0xffffu) | (v1 << 16);
            lo.y = (v2 & 0xffffu) | (v3 << 16);
            hi.x = (v0 >> 16) | (v1 & 0xffff0000u);
            hi.y = (v2 >> 16) | (v3 & 0xffff0000u);
            *(uint2*)(tl + (2 * j) * 100 + c0)     = lo;
            *(uint2*)(tl + (2 * j + 1) * 100 + c0) = hi;
        }
    }

    // ----- anchor prefetch into registers (issues before barrier) -----
    long base = (long)b * Cn * PLANE + (h << 7) + hb * 64;
    int p = wv * 16 + n16;
    float anc[6][4];
#pragma unroll
    for (int mt = 0; mt < 6; ++mt)
#pragma unroll
        for (int reg = 0; reg < 4; ++reg) {
            int o = mt * 16 + quad * 4 + reg;
            anc[mt][reg] = anchor[base + (long)o * PLANE + p];
        }

    __syncthreads();

    // B fragments: one 16-pixel n-tile per wave
    FragU Bf[3];
    {
        const short* bp = tl + p * 100 + quad * 8;
#pragma unroll
        for (int kb = 0; kb < 3; ++kb) {
            Bf[kb].u2[0] = *(const uint2*)(bp + kb * 32);
            Bf[kb].u2[1] = *(const uint2*)(bp + kb * 32 + 4);
        }
    }

    floatx4 acc[6];
#pragma unroll
    for (int mt = 0; mt < 6; ++mt)
        acc[mt] = (floatx4){0.f, 0.f, 0.f, 0.f};

#pragma unroll
    for (int mt = 0; mt < 6; ++mt) {
        int o = mt * 16 + n16;
        const short* apg = wl + o * 100 + quad * 8;
        FragU Af[3];
#pragma unroll
        for (int kb = 0; kb < 3; ++kb) {
            Af[kb].u2[0] = *(const uint2*)(apg + kb * 32);
            Af[kb].u2[1] = *(const uint2*)(apg + kb * 32 + 4);
        }
#pragma unroll
        for (int kb = 0; kb < 3; ++kb)
            acc[mt] = __builtin_amdgcn_mfma_f32_16x16x32_bf16(
                Af[kb].v, Bf[kb].v, acc[mt], 0, 0, 0);
    }

    // epilogue: BN_f + anchor(reg) + prelu
#pragma unroll
    for (int mt = 0; mt < 6; ++mt) {
#pragma unroll
        for (int reg = 0; reg < 4; ++reg) {
            int o = mt * 16 + quad * 4 + reg;
            long idx = base + (long)o * PLANE + p;
            float fused = acc[mt][reg] * sfsc[o] + sfof[o];
            float v = fused + anc[mt][reg];
            out[idx] = (v >= 0.f) ? v : saa[o] * v;
        }
    }
}

// ---------------------------------------------------------------------------
// K3: 4 blocks per (b,c) plane (32 rows each): row means -> xh (direct),
// column sums -> xw via atomicAdd (xw zeroed by k1; kF divides by Hn).
// ---------------------------------------------------------------------------
__global__ __launch_bounds__(256) void k3_means(
    const float* __restrict__ op, float* __restrict__ xh, float* __restrict__ xw)
{
    int blk = blockIdx.x;                // 768*4
    int bc  = blk >> 2;
    int q   = blk & 3;
    const float4* pl = (const float4*)(op + ((long)bc << 14) + (q << 12));
    int tid = threadIdx.x;
    int wq = tid & 31;
    int hg = tid >> 5;                   // 0..7
    __shared__ float cpart[8][Wn + 4];
    __shared__ float rpart[32];
    float4 csum = make_float4(0, 0, 0, 0);
#pragma unroll
    for (int k = 0; k < 4; ++k) {
        int hl = hg * 4 + k;             // local row 0..31
        float4 v = pl[hl * 32 + wq];
        csum.x += v.x; csum.y += v.y; csum.z += v.z; csum.w += v.w;
        float rs = v.x + v.y + v.z + v.w;
#pragma unroll
        for (int off = 16; off; off >>= 1) rs += __shfl_down(rs, off, 32);
        if (wq == 0) rpart[hl] = rs * (1.f / Wn);
    }
    cpart[hg][wq * 4 + 0] = csum.x;
    cpart[hg][wq * 4 + 1] = csum.y;
    cpart[hg][wq * 4 + 2] = csum.z;
    cpart[hg][wq * 4 + 3] = csum.w;
    __syncthreads();
    if (tid < 128) {
        float s = 0.f;
#pragma unroll
        for (int g = 0; g < 8; ++g) s += cpart[g][tid];
        atomicAdd(&xw[bc * Wn + tid], s);
    }
    if (tid < 32) xh[bc * Hn + q * 32 + tid] = rpart[tid];
}

// ---------------------------------------------------------------------------
// KF: fused coord-attention MLP + scale.  One block per (b,c) plane.
// ---------------------------------------------------------------------------
__global__ __launch_bounds__(256) void kf_att_scale(
    const float* __restrict__ xh, const float* __restrict__ xw,
    const float* __restrict__ w1,
    const float* __restrict__ g, const float* __restrict__ bb,
    const float* __restrict__ m, const float* __restrict__ v,
    const float* __restrict__ aa,
    const float* __restrict__ cwh, const float* __restrict__ cww,
    float* __restrict__ out)
{
    __shared__ float w1s[8 * Cn];
    __shared__ float sah[Hn];
    __shared__ float saw[Wn];

    int bc  = blockIdx.x;                // 768
    int b   = bc / Cn;
    int c   = bc % Cn;
    int p   = threadIdx.x;               // 0..255

    for (int e = p; e < 8 * Cn; e += 256) w1s[e] = w1[e];
    __syncthreads();

    bool isH = (p < Hn);
    const float* src = isH ? (xh + ((long)b * Cn) * Hn + p)
                           : (xw + ((long)b * Cn) * Wn + (p - Hn));
    float scale = isH ? 1.f : (1.f / Hn);

    float acc[8];
#pragma unroll
    for (int i = 0; i < 8; ++i) acc[i] = 0.f;
    for (int cc = 0; cc < Cn; ++cc) {
        float yv = src[(long)cc * Hn] * scale;
#pragma unroll
        for (int mip = 0; mip < 8; ++mip) acc[mip] += w1s[mip * Cn + cc] * yv;
    }
    const float* wsel = isH ? (cwh + c * 8) : (cww + c * 8);
    float s = 0.f;
#pragma unroll
    for (int mip = 0; mip < 8; ++mip) {
        float sc = g[mip] * rsqrtf(v[mip] + EPSV);
        float t = (acc[mip] - m[mip]) * sc + bb[mip];
        float yv = (t >= 0.f) ? t : aa[mip] * t;
        s += wsel[mip] * yv;
    }
    float av = 1.f / (1.f + expf(-s));
    if (isH) sah[p] = av; else saw[p - Hn] = av;
    __syncthreads();

    float4* p4 = (float4*)(out + ((long)bc << 14));
#pragma unroll
    for (int it = 0; it < 16; ++it) {
        int idx = p + it * 256;          // 0..4095 float4s
        int h = idx >> 5;
        int w4 = idx & 31;
        float4 vv = p4[idx];
        float ah = sah[h];
        float4 aw = *(float4*)&saw[w4 * 4];
        float4 r;
        r.x = vv.x * ah * aw.x;
        r.y = vv.y * ah * aw.y;
        r.z = vv.z * ah * aw.z;
        r.w = vv.w * ah * aw.w;
        p4[idx] = r;
    }
}

// ---------------------------------------------------------------------------
extern "C" void kernel_launch(void* const* d_in, const int* in_sizes, int n_in,
                              void* d_out, int out_size, void* d_ws, size_t ws_size,
                              hipStream_t stream)
{
    const float* x     = (const float*)d_in[0];
    const float* r_m   = (const float*)d_in[1];
    const float* wh_m  = (const float*)d_in[2];
    const float* ww_m  = (const float*)d_in[3];
    const float* r_l   = (const float*)d_in[4];
    const float* wh_l  = (const float*)d_in[5];
    const float* ww_l  = (const float*)d_in[6];
    const float* wfuse = (const float*)d_in[7];
    const float* bnf_g = (const float*)d_in[8];
    const float* bnf_b = (const float*)d_in[9];
    const float* bnf_m = (const float*)d_in[10];
    const float* bnf_v = (const float*)d_in[11];
    const float* dg_wh = (const float*)d_in[12];
    const float* dg_ww = (const float*)d_in[13];
    const float* dg_g  = (const float*)d_in[14];
    const float* dg_b  = (const float*)d_in[15];
    const float* dg_m  = (const float*)d_in[16];
    const float* dg_v  = (const float*)d_in[17];
    const float* act_a = (const float*)d_in[18];
    const float* ca_w1 = (const float*)d_in[19];
    const float* ca_g  = (const float*)d_in[20];
    const float* ca_b  = (const float*)d_in[21];
    const float* ca_m  = (const float*)d_in[22];
    const float* ca_v  = (const float*)d_in[23];
    const float* ca_a  = (const float*)d_in[24];
    const float* ca_wh = (const float*)d_in[25];
    const float* ca_ww = (const float*)d_in[26];

    float* ws     = (float*)d_ws;
    float* anchor = ws;                          // NIMG floats
    float* xh     = anchor + (size_t)NIMG;       // 98304
    float* xw     = xh + Bn * Cn * Hn;           // 98304
    float* wts    = xw + Bn * Cn * Wn;           // 192*48
    int*   cnt    = (int*)(wts + 2 * Cn * TAPN); // 192
    int*   offs   = cnt + 2 * Cn;                // 192*48
    short* t_bf   = (short*)(offs + 2 * Cn * TAPN); // NIMG shorts
    short* w_bf   = t_bf + (size_t)NIMG;         // 9216 shorts

    float* out = (float*)d_out;

    hipLaunchKernelGGL(k0_taps, dim3(1), dim3(256), 0, stream,
                       r_m, wh_m, ww_m, r_l, wh_l, ww_l, wfuse,
                       cnt, offs, wts, w_bf);
    hipLaunchKernelGGL(k1_axial, dim3(Bn * Cn * 2), dim3(512), 0, stream,
                       x, cnt, offs, wts, dg_wh, dg_ww, dg_g, dg_b, dg_m, dg_v,
                       t_bf, anchor, xw);
    hipLaunchKernelGGL(k2_pw, dim3(Bn * Hn * 2), dim3(256), 0, stream,
                       t_bf, anchor, w_bf, bnf_g, bnf_b, bnf_m, bnf_v, act_a, out);
    hipLaunchKernelGGL(k3_means, dim3(Bn * Cn * 4), dim3(256), 0, stream,
                       out, xh, xw);
    hipLaunchKernelGGL(kf_att_scale, dim3(Bn * Cn), dim3(256), 0, stream,
                       xh, xw, ca_w1, ca_g, ca_b, ca_m, ca_v, ca_a, ca_wh, ca_ww,
                       out);
}